// Round 3
// baseline (955.136 us; speedup 1.0000x reference)
//
#include <hip/hip_runtime.h>
#include <stdint.h>

#define N 8192

// DIAGNOSTIC ROUND: k1 repeated x2, k3 x8, k4 x8 (identical work each rep)
// so each kernel's dur/counters appear in rocprof top-5. True cost = dur/REP.
#define REP_K1 2
#define REP_K3 8
#define REP_K4 8

typedef __attribute__((ext_vector_type(8))) short sh8;
typedef __attribute__((ext_vector_type(4))) float f32x4;

static __device__ __forceinline__ unsigned short f2bf(float f) {
    union { float f; unsigned u; } v; v.f = f;
    unsigned r = v.u + 0x7FFF + ((v.u >> 16) & 1);   // round-to-nearest-even
    return (unsigned short)(r >> 16);
}

static __device__ __forceinline__ float bf2f(unsigned short h) {
    union { unsigned u; float f; } v; v.u = ((unsigned)h) << 16;
    return v.f;
}

// Pass 1: deg[i] = row-sum of adj; write bf16 copy of (adj + I).
__global__ __launch_bounds__(256) void k_deg_conv(const float* __restrict__ adj,
        unsigned short* __restrict__ abf, float* __restrict__ deg) {
    int wave = threadIdx.x >> 6, lane = threadIdx.x & 63;
    int row = blockIdx.x * 4 + wave;
    const float* arow = adj + (size_t)row * N;
    unsigned short* brow = abf + (size_t)row * N;
    for (int rep = 0; rep < REP_K1; ++rep) {
        float sum = 0.f;
        #pragma unroll 8
        for (int it = 0; it < N / 256; ++it) {        // 32 iters, float4 per lane
            int j = it * 256 + lane * 4;
            float4 v = *(const float4*)(arow + j);
            sum += (v.x + v.y) + (v.z + v.w);
            int d = row - j;                          // diag lands here iff d in [0,4)
            float x0 = v.x + ((d == 0) ? 1.f : 0.f);
            float x1 = v.y + ((d == 1) ? 1.f : 0.f);
            float x2 = v.z + ((d == 2) ? 1.f : 0.f);
            float x3 = v.w + ((d == 3) ? 1.f : 0.f);
            ushort4 o;
            o.x = f2bf(x0); o.y = f2bf(x1); o.z = f2bf(x2); o.w = f2bf(x3);
            *(ushort4*)(brow + j) = o;
        }
        #pragma unroll
        for (int m = 1; m < 64; m <<= 1) sum += __shfl_xor(sum, m);
        if (lane == 0) deg[row] = sum;
        asm volatile("" ::: "memory");
    }
}

// Pass 2 (single block): gmax, then per-node scalars s, y0 = s, y1 = s*deg_norm.
__global__ __launch_bounds__(1024) void k_scalars(const float* __restrict__ deg,
        float* __restrict__ s, float* __restrict__ y0, float* __restrict__ y1) {
    __shared__ float red[1024];
    int t = threadIdx.x;
    float m = 1.0f;
    for (int i = t; i < N; i += 1024) m = fmaxf(m, deg[i]);
    red[t] = m; __syncthreads();
    for (int sz = 512; sz > 0; sz >>= 1) {
        if (t < sz) red[t] = fmaxf(red[t], red[t + sz]);
        __syncthreads();
    }
    float gmax = red[0];
    for (int i = t; i < N; i += 1024) {
        float d = deg[i];
        float si = 1.0f / sqrtf(fmaxf(d + 1.0f, 1.0f));
        s[i] = si;
        y0[i] = si;
        y1[i] = si * (d / gmax);
    }
}

// Pass 3: one wave per row. z = a_row . [y0, y1]; h1 = relu(s_i*z@W1 + b1);
// store gT[c][i] = bf16(s_i * h1[i][c])  (transposed for MFMA B-operand reads).
__global__ __launch_bounds__(256) void k_layer1(const unsigned short* __restrict__ abf,
        const float* __restrict__ y0, const float* __restrict__ y1,
        const float* __restrict__ s, const float* __restrict__ W1,
        const float* __restrict__ b1, unsigned short* __restrict__ gT) {
    int wave = threadIdx.x >> 6;
    int lane = threadIdx.x & 63;
    int row = blockIdx.x * 4 + wave;
    const unsigned short* arow = abf + (size_t)row * N;
    for (int rep = 0; rep < REP_K3; ++rep) {
        float z0 = 0.f, z1 = 0.f;
        #pragma unroll 2
        for (int it = 0; it < N / 512; ++it) {   // 16 iters, 8 elems/lane/iter
            int j = it * 512 + lane * 8;
            sh8 a = *(const sh8*)(arow + j);
            float4 p0 = *(const float4*)(y0 + j);
            float4 p1 = *(const float4*)(y0 + j + 4);
            float4 q0 = *(const float4*)(y1 + j);
            float4 q1 = *(const float4*)(y1 + j + 4);
            float af[8];
            #pragma unroll
            for (int e = 0; e < 8; ++e) af[e] = bf2f((unsigned short)a[e]);
            z0 += af[0]*p0.x + af[1]*p0.y + af[2]*p0.z + af[3]*p0.w
                + af[4]*p1.x + af[5]*p1.y + af[6]*p1.z + af[7]*p1.w;
            z1 += af[0]*q0.x + af[1]*q0.y + af[2]*q0.z + af[3]*q0.w
                + af[4]*q1.x + af[5]*q1.y + af[6]*q1.z + af[7]*q1.w;
        }
        #pragma unroll
        for (int m = 1; m < 64; m <<= 1) {
            z0 += __shfl_xor(z0, m);
            z1 += __shfl_xor(z1, m);
        }
        float si = s[row];
        float h = si * (z0 * W1[lane] + z1 * W1[64 + lane]) + b1[lane];
        h = fmaxf(h, 0.f);
        gT[(size_t)lane * N + row] = f2bf(si * h);
        asm volatile("" ::: "memory");
    }
}

// Pass 4: t = a @ g  (M=8192, N=64, K=8192, bf16 MFMA 16x16x32),
// out = s_i * (t @ W2) + b2. Block = 16 rows, 4 waves K-split (2048 each).
__global__ __launch_bounds__(256) void k_layer2(const unsigned short* __restrict__ abf,
        const unsigned short* __restrict__ gT, const float* __restrict__ s,
        const float* __restrict__ W2, const float* __restrict__ b2,
        float* __restrict__ out) {
    __shared__ float tl[4][16 * 65];
    int tid = threadIdx.x;
    int wave = tid >> 6, lane = tid & 63;
    int r0 = blockIdx.x * 16;
    int arow = r0 + (lane & 15);
    int kb0 = wave * 2048 + ((lane >> 4) * 8);
    const unsigned short* aptr = abf + (size_t)arow * N + kb0;
    const unsigned short* gbase = gT + kb0;
    int col = lane & 15;
    for (int rep = 0; rep < REP_K4; ++rep) {
        __syncthreads();   // protect tl reuse across reps
        f32x4 acc0 = {0,0,0,0}, acc1 = {0,0,0,0}, acc2 = {0,0,0,0}, acc3 = {0,0,0,0};
        #pragma unroll 4
        for (int kk = 0; kk < 64; ++kk) {       // 64 * 32 = 2048 K per wave
            sh8 a  = *(const sh8*)(aptr + kk * 32);
            sh8 b0 = *(const sh8*)(gbase + (size_t)(col      ) * N + kk * 32);
            sh8 b1v= *(const sh8*)(gbase + (size_t)(col + 16) * N + kk * 32);
            sh8 b2v= *(const sh8*)(gbase + (size_t)(col + 32) * N + kk * 32);
            sh8 b3v= *(const sh8*)(gbase + (size_t)(col + 48) * N + kk * 32);
            acc0 = __builtin_amdgcn_mfma_f32_16x16x32_bf16(a, b0,  acc0, 0, 0, 0);
            acc1 = __builtin_amdgcn_mfma_f32_16x16x32_bf16(a, b1v, acc1, 0, 0, 0);
            acc2 = __builtin_amdgcn_mfma_f32_16x16x32_bf16(a, b2v, acc2, 0, 0, 0);
            acc3 = __builtin_amdgcn_mfma_f32_16x16x32_bf16(a, b3v, acc3, 0, 0, 0);
        }
        // C/D layout (m89-verified): col = lane&15, row = (lane>>4)*4 + reg
        int lr = (lane >> 4) * 4, lc = lane & 15;
        #pragma unroll
        for (int r = 0; r < 4; ++r) {
            tl[wave][(lr + r) * 65 + lc     ] = acc0[r];
            tl[wave][(lr + r) * 65 + lc + 16] = acc1[r];
            tl[wave][(lr + r) * 65 + lc + 32] = acc2[r];
            tl[wave][(lr + r) * 65 + lc + 48] = acc3[r];
        }
        __syncthreads();
        // reduce the 4 K-split partials into tl[0]
        for (int v = tid; v < 16 * 64; v += 256) {
            int idx = (v >> 6) * 65 + (v & 63);
            tl[0][idx] = tl[0][idx] + tl[1][idx] + tl[2][idx] + tl[3][idx];
        }
        __syncthreads();
        // epilogue: out[row][c2] = s[row] * dot(t[row,:], W2[:,c2]) + b2[c2]
        int c2 = tid & 63, rg = tid >> 6;
        float acc[4] = {0.f, 0.f, 0.f, 0.f};
        for (int c = 0; c < 64; ++c) {
            float w = W2[c * 64 + c2];
            #pragma unroll
            for (int r = 0; r < 4; ++r) acc[r] += tl[0][(rg * 4 + r) * 65 + c] * w;
        }
        float bc = b2[c2];
        #pragma unroll
        for (int r = 0; r < 4; ++r) {
            int row = r0 + rg * 4 + r;
            out[(size_t)row * 64 + c2] = s[row] * acc[r] + bc;
        }
        asm volatile("" ::: "memory");
    }
}

extern "C" void kernel_launch(void* const* d_in, const int* in_sizes, int n_in,
                              void* d_out, int out_size, void* d_ws, size_t ws_size,
                              hipStream_t stream) {
    const float* adj = (const float*)d_in[0];
    const float* W1  = (const float*)d_in[1];
    const float* b1  = (const float*)d_in[2];
    const float* W2  = (const float*)d_in[3];
    const float* b2  = (const float*)d_in[4];
    float* out = (float*)d_out;

    char* ws = (char*)d_ws;
    unsigned short* abf = (unsigned short*)ws;                              // 128 MB
    unsigned short* gT  = (unsigned short*)(ws + (size_t)N * N * 2);        // 1 MB
    float* deg = (float*)(ws + (size_t)N * N * 2 + (size_t)64 * N * 2);
    float* s   = deg + N;
    float* y0  = s + N;
    float* y1  = y0 + N;

    hipLaunchKernelGGL(k_deg_conv, dim3(N / 4),  dim3(256),  0, stream, adj, abf, deg);
    hipLaunchKernelGGL(k_scalars,  dim3(1),      dim3(1024), 0, stream, deg, s, y0, y1);
    hipLaunchKernelGGL(k_layer1,   dim3(N / 4),  dim3(256),  0, stream, abf, y0, y1, s, W1, b1, gT);
    hipLaunchKernelGGL(k_layer2,   dim3(N / 16), dim3(256),  0, stream, abf, gT, s, W2, b2, out);
}

// Round 4
// 212.029 us; speedup vs baseline: 4.5048x; 4.5048x over previous
//
#include <hip/hip_runtime.h>
#include <stdint.h>

#define N 8192
#define KSPLIT 8

typedef __attribute__((ext_vector_type(8))) short sh8;
typedef __attribute__((ext_vector_type(4))) float f32x4;

static __device__ __forceinline__ unsigned short f2bf(float f) {
    union { float f; unsigned u; } v; v.f = f;
    unsigned r = v.u + 0x7FFF + ((v.u >> 16) & 1);   // round-to-nearest-even
    return (unsigned short)(r >> 16);
}

static __device__ __forceinline__ float bf2f(unsigned short h) {
    union { unsigned u; float f; } v; v.u = ((unsigned)h) << 16;
    return v.f;
}

// Pass 1: deg[i] = row-sum of adj; write bf16 copy of (adj + I).
__global__ __launch_bounds__(256) void k_deg_conv(const float* __restrict__ adj,
        unsigned short* __restrict__ abf, float* __restrict__ deg) {
    int wave = threadIdx.x >> 6, lane = threadIdx.x & 63;
    int row = blockIdx.x * 4 + wave;
    const float* arow = adj + (size_t)row * N;
    unsigned short* brow = abf + (size_t)row * N;
    float sum = 0.f;
    #pragma unroll 8
    for (int it = 0; it < N / 256; ++it) {        // 32 iters, float4 per lane
        int j = it * 256 + lane * 4;
        float4 v = *(const float4*)(arow + j);
        sum += (v.x + v.y) + (v.z + v.w);
        int d = row - j;                          // diag lands here iff d in [0,4)
        float x0 = v.x + ((d == 0) ? 1.f : 0.f);
        float x1 = v.y + ((d == 1) ? 1.f : 0.f);
        float x2 = v.z + ((d == 2) ? 1.f : 0.f);
        float x3 = v.w + ((d == 3) ? 1.f : 0.f);
        ushort4 o;
        o.x = f2bf(x0); o.y = f2bf(x1); o.z = f2bf(x2); o.w = f2bf(x3);
        *(ushort4*)(brow + j) = o;
    }
    #pragma unroll
    for (int m = 1; m < 64; m <<= 1) sum += __shfl_xor(sum, m);
    if (lane == 0) deg[row] = sum;
}

// Pass 2 (single block): gmax, then per-node scalars s, y0 = s, y1 = s*deg_norm.
__global__ __launch_bounds__(1024) void k_scalars(const float* __restrict__ deg,
        float* __restrict__ s, float* __restrict__ y0, float* __restrict__ y1) {
    __shared__ float red[1024];
    int t = threadIdx.x;
    float m = 1.0f;
    for (int i = t; i < N; i += 1024) m = fmaxf(m, deg[i]);
    red[t] = m; __syncthreads();
    for (int sz = 512; sz > 0; sz >>= 1) {
        if (t < sz) red[t] = fmaxf(red[t], red[t + sz]);
        __syncthreads();
    }
    float gmax = red[0];
    for (int i = t; i < N; i += 1024) {
        float d = deg[i];
        float si = 1.0f / sqrtf(fmaxf(d + 1.0f, 1.0f));
        s[i] = si;
        y0[i] = si;
        y1[i] = si * (d / gmax);
    }
}

// Pass 3: one wave per row. z = a_row . [y0, y1]; h1 = relu(s_i*z@W1 + b1);
// store gT[c][i] = bf16(s_i * h1[i][c])  (transposed for MFMA B-operand reads).
__global__ __launch_bounds__(256) void k_layer1(const unsigned short* __restrict__ abf,
        const float* __restrict__ y0, const float* __restrict__ y1,
        const float* __restrict__ s, const float* __restrict__ W1,
        const float* __restrict__ b1, unsigned short* __restrict__ gT) {
    int wave = threadIdx.x >> 6;
    int lane = threadIdx.x & 63;
    int row = blockIdx.x * 4 + wave;
    const unsigned short* arow = abf + (size_t)row * N;
    float z0 = 0.f, z1 = 0.f;
    #pragma unroll 2
    for (int it = 0; it < N / 512; ++it) {   // 16 iters, 8 elems/lane/iter
        int j = it * 512 + lane * 8;
        sh8 a = *(const sh8*)(arow + j);
        float4 p0 = *(const float4*)(y0 + j);
        float4 p1 = *(const float4*)(y0 + j + 4);
        float4 q0 = *(const float4*)(y1 + j);
        float4 q1 = *(const float4*)(y1 + j + 4);
        float af[8];
        #pragma unroll
        for (int e = 0; e < 8; ++e) af[e] = bf2f((unsigned short)a[e]);
        z0 += af[0]*p0.x + af[1]*p0.y + af[2]*p0.z + af[3]*p0.w
            + af[4]*p1.x + af[5]*p1.y + af[6]*p1.z + af[7]*p1.w;
        z1 += af[0]*q0.x + af[1]*q0.y + af[2]*q0.z + af[3]*q0.w
            + af[4]*q1.x + af[5]*q1.y + af[6]*q1.z + af[7]*q1.w;
    }
    #pragma unroll
    for (int m = 1; m < 64; m <<= 1) {
        z0 += __shfl_xor(z0, m);
        z1 += __shfl_xor(z1, m);
    }
    float si = s[row];
    float h = si * (z0 * W1[lane] + z1 * W1[64 + lane]) + b1[lane];
    h = fmaxf(h, 0.f);
    gT[(size_t)lane * N + row] = f2bf(si * h);
}

// Pass 4a: partial t = A @ g over a K-slab. Grid = (N/16) x KSPLIT.
// Block = 16 rows x 1024 K, 4 waves x 256 K each; f32 partials to ws.
__global__ __launch_bounds__(256) void k_layer2a(const unsigned short* __restrict__ abf,
        const unsigned short* __restrict__ gT, float* __restrict__ tpart) {
    __shared__ float tl[4][16 * 65];
    int tid = threadIdx.x;
    int wave = tid >> 6, lane = tid & 63;
    int r0 = blockIdx.x * 16;
    int kb = blockIdx.y;
    int arow = r0 + (lane & 15);
    int kbase = kb * (N / KSPLIT) + wave * (N / KSPLIT / 4) + ((lane >> 4) * 8);
    const unsigned short* aptr = abf + (size_t)arow * N + kbase;
    const unsigned short* gbase = gT + kbase;
    int col = lane & 15;
    f32x4 acc0 = {0,0,0,0}, acc1 = {0,0,0,0}, acc2 = {0,0,0,0}, acc3 = {0,0,0,0};
    #pragma unroll 4
    for (int kk = 0; kk < (N / KSPLIT / 4) / 32; ++kk) {   // 8 iters x K=32
        sh8 a  = *(const sh8*)(aptr + kk * 32);
        sh8 b0 = *(const sh8*)(gbase + (size_t)(col      ) * N + kk * 32);
        sh8 b1v= *(const sh8*)(gbase + (size_t)(col + 16) * N + kk * 32);
        sh8 b2v= *(const sh8*)(gbase + (size_t)(col + 32) * N + kk * 32);
        sh8 b3v= *(const sh8*)(gbase + (size_t)(col + 48) * N + kk * 32);
        acc0 = __builtin_amdgcn_mfma_f32_16x16x32_bf16(a, b0,  acc0, 0, 0, 0);
        acc1 = __builtin_amdgcn_mfma_f32_16x16x32_bf16(a, b1v, acc1, 0, 0, 0);
        acc2 = __builtin_amdgcn_mfma_f32_16x16x32_bf16(a, b2v, acc2, 0, 0, 0);
        acc3 = __builtin_amdgcn_mfma_f32_16x16x32_bf16(a, b3v, acc3, 0, 0, 0);
    }
    // C/D layout (m89-verified): col = lane&15, row = (lane>>4)*4 + reg
    int lr = (lane >> 4) * 4, lc = lane & 15;
    #pragma unroll
    for (int r = 0; r < 4; ++r) {
        tl[wave][(lr + r) * 65 + lc     ] = acc0[r];
        tl[wave][(lr + r) * 65 + lc + 16] = acc1[r];
        tl[wave][(lr + r) * 65 + lc + 32] = acc2[r];
        tl[wave][(lr + r) * 65 + lc + 48] = acc3[r];
    }
    __syncthreads();
    // reduce 4 waves' partials and write 16x64 f32 to tpart[kb]
    #pragma unroll
    for (int v = tid; v < 16 * 64; v += 256) {
        int rr = v >> 6, cc = v & 63;
        int idx = rr * 65 + cc;
        float sum = tl[0][idx] + tl[1][idx] + tl[2][idx] + tl[3][idx];
        tpart[(size_t)kb * N * 64 + (size_t)(r0 + rr) * 64 + cc] = sum;
    }
}

// Pass 4b: t = sum of KSPLIT partials; out = s .* (t @ W2) + b2.
// Block = 4 rows x 64 cols = 256 threads.
__global__ __launch_bounds__(256) void k_layer2b(const float* __restrict__ tpart,
        const float* __restrict__ s, const float* __restrict__ W2,
        const float* __restrict__ b2, float* __restrict__ out) {
    __shared__ float ts[4][64];
    int tid = threadIdx.x;
    int r0 = blockIdx.x * 4;
    int rg = tid >> 6, c = tid & 63;
    float v = 0.f;
    #pragma unroll
    for (int kb = 0; kb < KSPLIT; ++kb)
        v += tpart[(size_t)kb * N * 64 + (size_t)(r0 + rg) * 64 + c];
    ts[rg][c] = v;
    __syncthreads();
    float acc = 0.f;
    #pragma unroll 8
    for (int cc = 0; cc < 64; ++cc)
        acc += ts[rg][cc] * W2[cc * 64 + c];
    int row = r0 + rg;
    out[(size_t)row * 64 + c] = s[row] * acc + b2[c];
}

extern "C" void kernel_launch(void* const* d_in, const int* in_sizes, int n_in,
                              void* d_out, int out_size, void* d_ws, size_t ws_size,
                              hipStream_t stream) {
    const float* adj = (const float*)d_in[0];
    const float* W1  = (const float*)d_in[1];
    const float* b1  = (const float*)d_in[2];
    const float* W2  = (const float*)d_in[3];
    const float* b2  = (const float*)d_in[4];
    float* out = (float*)d_out;

    char* ws = (char*)d_ws;
    unsigned short* abf = (unsigned short*)ws;                              // 128 MB
    unsigned short* gT  = (unsigned short*)(ws + (size_t)N * N * 2);        // 1 MB
    float* tpart = (float*)(ws + (size_t)N * N * 2 + (size_t)64 * N * 2);   // 16 MB
    float* deg = tpart + (size_t)KSPLIT * N * 64;
    float* s   = deg + N;
    float* y0  = s + N;
    float* y1  = y0 + N;

    hipLaunchKernelGGL(k_deg_conv, dim3(N / 4),  dim3(256),  0, stream, adj, abf, deg);
    hipLaunchKernelGGL(k_scalars,  dim3(1),      dim3(1024), 0, stream, deg, s, y0, y1);
    hipLaunchKernelGGL(k_layer1,   dim3(N / 4),  dim3(256),  0, stream, abf, y0, y1, s, W1, b1, gT);
    hipLaunchKernelGGL(k_layer2a,  dim3(N / 16, KSPLIT), dim3(256), 0, stream, abf, gT, tpart);
    hipLaunchKernelGGL(k_layer2b,  dim3(N / 4),  dim3(256),  0, stream, tpart, s, W2, b2, out);
}

// Round 5
// 153.341 us; speedup vs baseline: 6.2289x; 1.3827x over previous
//
#include <hip/hip_runtime.h>
#include <stdint.h>

#define N 8192
#define KSPLIT 8               // K-slabs for k_layer2a
#define BK 128                 // K per LDS tile
#define KPB (N / KSPLIT)       // 1024 K per block
#define TILES (KPB / BK)       // 8 tiles per block

typedef __attribute__((ext_vector_type(8))) short sh8;
typedef __attribute__((ext_vector_type(4))) float f32x4;

static __device__ __forceinline__ unsigned short f2bf(float f) {
    union { float f; unsigned u; } v; v.f = f;
    unsigned r = v.u + 0x7FFF + ((v.u >> 16) & 1);   // round-to-nearest-even
    return (unsigned short)(r >> 16);
}

static __device__ __forceinline__ float bf2f(unsigned short h) {
    union { unsigned u; float f; } v; v.u = ((unsigned)h) << 16;
    return v.f;
}

static __device__ __forceinline__ void glds16(const unsigned short* g, unsigned short* l) {
    __builtin_amdgcn_global_load_lds(
        (const __attribute__((address_space(1))) void*)g,
        (__attribute__((address_space(3))) void*)l, 16, 0, 0);
}

// Pass 1 (R1 version, measured fastest): deg row-sum + bf16 copy of (adj + I).
__global__ __launch_bounds__(256) void k_deg_conv(const float* __restrict__ adj,
        unsigned short* __restrict__ abf, float* __restrict__ deg) {
    int row = blockIdx.x;
    const float* arow = adj + (size_t)row * N;
    unsigned short* brow = abf + (size_t)row * N;
    int t = threadIdx.x;
    float sum = 0.f;
    #pragma unroll
    for (int it = 0; it < N / 1024; ++it) {      // 8 iters of float4 per thread
        int j = (it * 256 + t) * 4;
        float4 v = *(const float4*)(arow + j);
        sum += v.x + v.y + v.z + v.w;
        int d = row - j;                          // diag lands here iff d in [0,4)
        float x0 = v.x + ((d == 0) ? 1.f : 0.f);
        float x1 = v.y + ((d == 1) ? 1.f : 0.f);
        float x2 = v.z + ((d == 2) ? 1.f : 0.f);
        float x3 = v.w + ((d == 3) ? 1.f : 0.f);
        ushort4 o;
        o.x = f2bf(x0); o.y = f2bf(x1); o.z = f2bf(x2); o.w = f2bf(x3);
        *(ushort4*)(brow + j) = o;
    }
    __shared__ float red[256];
    red[t] = sum; __syncthreads();
    for (int sz = 128; sz > 0; sz >>= 1) {
        if (t < sz) red[t] += red[t + sz];
        __syncthreads();
    }
    if (t == 0) deg[row] = red[0];
}

// Pass 2 (single block): gmax, then per-node scalars s, y0 = s, y1 = s*deg_norm.
__global__ __launch_bounds__(1024) void k_scalars(const float* __restrict__ deg,
        float* __restrict__ s, float* __restrict__ y0, float* __restrict__ y1) {
    __shared__ float red[1024];
    int t = threadIdx.x;
    float m = 1.0f;
    for (int i = t; i < N; i += 1024) m = fmaxf(m, deg[i]);
    red[t] = m; __syncthreads();
    for (int sz = 512; sz > 0; sz >>= 1) {
        if (t < sz) red[t] = fmaxf(red[t], red[t + sz]);
        __syncthreads();
    }
    float gmax = red[0];
    for (int i = t; i < N; i += 1024) {
        float d = deg[i];
        float si = 1.0f / sqrtf(fmaxf(d + 1.0f, 1.0f));
        s[i] = si;
        y0[i] = si;
        y1[i] = si * (d / gmax);
    }
}

// Pass 3: one wave per row. z = a_row . [y0, y1]; h1 = relu(s_i*z@W1 + b1);
// store gT[c][i] = bf16(s_i * h1[i][c])  (transposed for MFMA B-operand reads).
__global__ __launch_bounds__(256) void k_layer1(const unsigned short* __restrict__ abf,
        const float* __restrict__ y0, const float* __restrict__ y1,
        const float* __restrict__ s, const float* __restrict__ W1,
        const float* __restrict__ b1, unsigned short* __restrict__ gT) {
    int wave = threadIdx.x >> 6;
    int lane = threadIdx.x & 63;
    int row = blockIdx.x * 4 + wave;
    const unsigned short* arow = abf + (size_t)row * N;
    float z0 = 0.f, z1 = 0.f;
    #pragma unroll 2
    for (int it = 0; it < N / 512; ++it) {   // 16 iters, 8 elems/lane/iter
        int j = it * 512 + lane * 8;
        sh8 a = *(const sh8*)(arow + j);
        float4 p0 = *(const float4*)(y0 + j);
        float4 p1 = *(const float4*)(y0 + j + 4);
        float4 q0 = *(const float4*)(y1 + j);
        float4 q1 = *(const float4*)(y1 + j + 4);
        float af[8];
        #pragma unroll
        for (int e = 0; e < 8; ++e) af[e] = bf2f((unsigned short)a[e]);
        z0 += af[0]*p0.x + af[1]*p0.y + af[2]*p0.z + af[3]*p0.w
            + af[4]*p1.x + af[5]*p1.y + af[6]*p1.z + af[7]*p1.w;
        z1 += af[0]*q0.x + af[1]*q0.y + af[2]*q0.z + af[3]*q0.w
            + af[4]*q1.x + af[5]*q1.y + af[6]*q1.z + af[7]*q1.w;
    }
    #pragma unroll
    for (int m = 1; m < 64; m <<= 1) {
        z0 += __shfl_xor(z0, m);
        z1 += __shfl_xor(z1, m);
    }
    float si = s[row];
    float h = si * (z0 * W1[lane] + z1 * W1[64 + lane]) + b1[lane];
    h = fmaxf(h, 0.f);
    gT[(size_t)lane * N + row] = f2bf(si * h);
}

// Pass 4a: partial t = A @ g over a K-slab, LDS-staged GEMM.
// Grid (N/64, KSPLIT); block 256 = 4 waves; wave w owns rows w*16..w*16+15.
// LDS tiles [64][BK] bf16, XOR-swizzled (chunk ^ (row&7)) via inverse-swizzled
// global_load_lds source (rule #21); double-buffered, 2-phase schedule (T3-min).
__global__ __launch_bounds__(256) void k_layer2a(const unsigned short* __restrict__ abf,
        const unsigned short* __restrict__ gT, float* __restrict__ tpart) {
    __shared__ unsigned short Al[2][64 * BK];   // 16 KB each
    __shared__ unsigned short Bl[2][64 * BK];
    int tid = threadIdx.x;
    int wave = tid >> 6, lane = tid & 63;
    int r0 = blockIdx.x * 64;
    int kbase0 = blockIdx.y * KPB;

    int r = lane & 15, q = lane >> 4;

    f32x4 acc0 = {0,0,0,0}, acc1 = {0,0,0,0}, acc2 = {0,0,0,0}, acc3 = {0,0,0,0};

    // ---- staging: 4 calls each for A and B per tile; lane-linear LDS dest,
    // inverse-swizzled global source (chunk sch = ch ^ (row&7), 16B chunks).
    #define STAGE(buf, kbase)                                                   \
        do {                                                                    \
            _Pragma("unroll")                                                   \
            for (int i = 0; i < 4; ++i) {                                       \
                int bidx = i * 256 + wave * 64;                                 \
                int idx = bidx + lane;                                          \
                int srow = idx >> 4, sch = (idx & 15) ^ (srow & 7);             \
                glds16(abf + (size_t)(r0 + srow) * N + (kbase) + sch * 8,       \
                       &Al[buf][bidx * 8]);                                     \
                glds16(gT + (size_t)srow * N + (kbase) + sch * 8,               \
                       &Bl[buf][bidx * 8]);                                     \
            }                                                                   \
        } while (0)

    STAGE(0, kbase0);
    __syncthreads();

    for (int t = 0; t < TILES; ++t) {
        int cur = t & 1;
        if (t + 1 < TILES) STAGE(cur ^ 1, kbase0 + (t + 1) * BK);
        int arow = wave * 16 + r;
        #pragma unroll
        for (int ks = 0; ks < 4; ++ks) {            // K-steps of 32 within BK
            int ch = ((ks * 4 + q) ^ (r & 7)) * 8;  // swizzled element offset
            sh8 a  = *(const sh8*)&Al[cur][arow * BK + ch];
            sh8 b0 = *(const sh8*)&Bl[cur][(r     ) * BK + ch];
            sh8 b1 = *(const sh8*)&Bl[cur][(r + 16) * BK + ch];
            sh8 b2 = *(const sh8*)&Bl[cur][(r + 32) * BK + ch];
            sh8 b3 = *(const sh8*)&Bl[cur][(r + 48) * BK + ch];
            acc0 = __builtin_amdgcn_mfma_f32_16x16x32_bf16(a, b0, acc0, 0, 0, 0);
            acc1 = __builtin_amdgcn_mfma_f32_16x16x32_bf16(a, b1, acc1, 0, 0, 0);
            acc2 = __builtin_amdgcn_mfma_f32_16x16x32_bf16(a, b2, acc2, 0, 0, 0);
            acc3 = __builtin_amdgcn_mfma_f32_16x16x32_bf16(a, b3, acc3, 0, 0, 0);
        }
        __syncthreads();   // drains vmcnt(0): next-tile stage has landed
    }
    #undef STAGE

    // C/D layout (m89-verified): col = lane&15, row = (lane>>4)*4 + reg
    float* tp = tpart + (size_t)blockIdx.y * N * 64;
    int growb = r0 + wave * 16 + q * 4;
    #pragma unroll
    for (int rr = 0; rr < 4; ++rr) {
        tp[(size_t)(growb + rr) * 64 + r     ] = acc0[rr];
        tp[(size_t)(growb + rr) * 64 + r + 16] = acc1[rr];
        tp[(size_t)(growb + rr) * 64 + r + 32] = acc2[rr];
        tp[(size_t)(growb + rr) * 64 + r + 48] = acc3[rr];
    }
}

// Pass 4b: t = sum of KSPLIT partials; out = s .* (t @ W2) + b2.
__global__ __launch_bounds__(256) void k_layer2b(const float* __restrict__ tpart,
        const float* __restrict__ s, const float* __restrict__ W2,
        const float* __restrict__ b2, float* __restrict__ out) {
    __shared__ float ts[4][64];
    int tid = threadIdx.x;
    int r0 = blockIdx.x * 4;
    int rg = tid >> 6, c = tid & 63;
    float v = 0.f;
    #pragma unroll
    for (int kb = 0; kb < KSPLIT; ++kb)
        v += tpart[(size_t)kb * N * 64 + (size_t)(r0 + rg) * 64 + c];
    ts[rg][c] = v;
    __syncthreads();
    float acc = 0.f;
    #pragma unroll 8
    for (int cc = 0; cc < 64; ++cc)
        acc += ts[rg][cc] * W2[cc * 64 + c];
    int row = r0 + rg;
    out[(size_t)row * 64 + c] = s[row] * acc + b2[c];
}

extern "C" void kernel_launch(void* const* d_in, const int* in_sizes, int n_in,
                              void* d_out, int out_size, void* d_ws, size_t ws_size,
                              hipStream_t stream) {
    const float* adj = (const float*)d_in[0];
    const float* W1  = (const float*)d_in[1];
    const float* b1  = (const float*)d_in[2];
    const float* W2  = (const float*)d_in[3];
    const float* b2  = (const float*)d_in[4];
    float* out = (float*)d_out;

    char* ws = (char*)d_ws;
    unsigned short* abf = (unsigned short*)ws;                              // 128 MB
    unsigned short* gT  = (unsigned short*)(ws + (size_t)N * N * 2);        // 1 MB
    float* tpart = (float*)(ws + (size_t)N * N * 2 + (size_t)64 * N * 2);   // 16 MB
    float* deg = tpart + (size_t)KSPLIT * N * 64;
    float* s   = deg + N;
    float* y0  = s + N;
    float* y1  = y0 + N;

    hipLaunchKernelGGL(k_deg_conv, dim3(N),      dim3(256),  0, stream, adj, abf, deg);
    hipLaunchKernelGGL(k_scalars,  dim3(1),      dim3(1024), 0, stream, deg, s, y0, y1);
    hipLaunchKernelGGL(k_layer1,   dim3(N / 4),  dim3(256),  0, stream, abf, y0, y1, s, W1, b1, gT);
    hipLaunchKernelGGL(k_layer2a,  dim3(N / 64, KSPLIT), dim3(256), 0, stream, abf, gT, tpart);
    hipLaunchKernelGGL(k_layer2b,  dim3(N / 4),  dim3(256),  0, stream, tpart, s, W2, b2, out);
}

// Round 6
// 142.240 us; speedup vs baseline: 6.7150x; 1.0780x over previous
//
#include <hip/hip_runtime.h>
#include <stdint.h>

#define N 8192
#define KSPLIT 8               // K-slabs for k_layer2a
#define BK 64                  // K per LDS tile (32 KB total LDS -> 5 blocks/CU)
#define KPB (N / KSPLIT)       // 1024 K per block
#define TILES (KPB / BK)       // 16 tiles per block

typedef __attribute__((ext_vector_type(8))) short sh8;
typedef __attribute__((ext_vector_type(4))) float f32x4;

static __device__ __forceinline__ unsigned short f2bf(float f) {
    union { float f; unsigned u; } v; v.f = f;
    unsigned r = v.u + 0x7FFF + ((v.u >> 16) & 1);   // round-to-nearest-even
    return (unsigned short)(r >> 16);
}

static __device__ __forceinline__ float bf2f(unsigned short h) {
    union { unsigned u; float f; } v; v.u = ((unsigned)h) << 16;
    return v.f;
}

static __device__ __forceinline__ float bflo(unsigned u) {
    union { unsigned u; float f; } v; v.u = u << 16;
    return v.f;
}

static __device__ __forceinline__ float bfhi(unsigned u) {
    union { unsigned u; float f; } v; v.u = u & 0xFFFF0000u;
    return v.f;
}

static __device__ __forceinline__ void glds16(const unsigned short* g, unsigned short* l) {
    __builtin_amdgcn_global_load_lds(
        (const __attribute__((address_space(1))) void*)g,
        (__attribute__((address_space(3))) void*)l, 16, 0, 0);
}

// Pass 1: deg row-sum + bf16 copy of (adj + I). Block-per-row (measured best).
__global__ __launch_bounds__(256) void k_deg_conv(const float* __restrict__ adj,
        unsigned short* __restrict__ abf, float* __restrict__ deg) {
    int row = blockIdx.x;
    const float* arow = adj + (size_t)row * N;
    unsigned short* brow = abf + (size_t)row * N;
    int t = threadIdx.x;
    float sum = 0.f;
    #pragma unroll
    for (int it = 0; it < N / 1024; ++it) {      // 8 iters of float4 per thread
        int j = (it * 256 + t) * 4;
        float4 v = *(const float4*)(arow + j);
        sum += v.x + v.y + v.z + v.w;
        int d = row - j;                          // diag lands here iff d in [0,4)
        float x0 = v.x + ((d == 0) ? 1.f : 0.f);
        float x1 = v.y + ((d == 1) ? 1.f : 0.f);
        float x2 = v.z + ((d == 2) ? 1.f : 0.f);
        float x3 = v.w + ((d == 3) ? 1.f : 0.f);
        ushort4 o;
        o.x = f2bf(x0); o.y = f2bf(x1); o.z = f2bf(x2); o.w = f2bf(x3);
        *(ushort4*)(brow + j) = o;
    }
    __shared__ float red[256];
    red[t] = sum; __syncthreads();
    for (int sz = 128; sz > 0; sz >>= 1) {
        if (t < sz) red[t] += red[t + sz];
        __syncthreads();
    }
    if (t == 0) deg[row] = red[0];
}

// Pass 2 (single block): gmax; s (f32); yb[j] = pack(bf16(y1), bf16(y0)).
__global__ __launch_bounds__(1024) void k_scalars(const float* __restrict__ deg,
        float* __restrict__ s, unsigned* __restrict__ yb) {
    __shared__ float red[1024];
    int t = threadIdx.x;
    float m = 1.0f;
    for (int i = t; i < N; i += 1024) m = fmaxf(m, deg[i]);
    red[t] = m; __syncthreads();
    for (int sz = 512; sz > 0; sz >>= 1) {
        if (t < sz) red[t] = fmaxf(red[t], red[t + sz]);
        __syncthreads();
    }
    float gmax = red[0];
    for (int i = t; i < N; i += 1024) {
        float d = deg[i];
        float si = 1.0f / sqrtf(fmaxf(d + 1.0f, 1.0f));
        s[i] = si;
        unsigned lo = f2bf(si);
        unsigned hi = f2bf(si * (d / gmax));
        yb[i] = (hi << 16) | lo;
    }
}

// Pass 3: one wave per row. z = a_row . [y0, y1] (y packed bf16x2);
// h1 = relu(s_i*z@W1 + b1); store gT[c][i] = bf16(s_i * h1[i][c]).
__global__ __launch_bounds__(256) void k_layer1(const unsigned short* __restrict__ abf,
        const unsigned* __restrict__ yb, const float* __restrict__ s,
        const float* __restrict__ W1, const float* __restrict__ b1,
        unsigned short* __restrict__ gT) {
    int wave = threadIdx.x >> 6;
    int lane = threadIdx.x & 63;
    int row = blockIdx.x * 4 + wave;
    const unsigned short* arow = abf + (size_t)row * N;
    float z0 = 0.f, z1 = 0.f;
    #pragma unroll 4
    for (int it = 0; it < N / 512; ++it) {   // 16 iters, 8 elems/lane/iter
        int j = it * 512 + lane * 8;
        sh8 a = *(const sh8*)(arow + j);
        uint4 w0 = *(const uint4*)(yb + j);
        uint4 w1 = *(const uint4*)(yb + j + 4);
        float a0 = bf2f((unsigned short)a[0]), a1 = bf2f((unsigned short)a[1]);
        float a2 = bf2f((unsigned short)a[2]), a3 = bf2f((unsigned short)a[3]);
        float a4 = bf2f((unsigned short)a[4]), a5 = bf2f((unsigned short)a[5]);
        float a6 = bf2f((unsigned short)a[6]), a7 = bf2f((unsigned short)a[7]);
        z0 += a0 * bflo(w0.x) + a1 * bflo(w0.y) + a2 * bflo(w0.z) + a3 * bflo(w0.w)
            + a4 * bflo(w1.x) + a5 * bflo(w1.y) + a6 * bflo(w1.z) + a7 * bflo(w1.w);
        z1 += a0 * bfhi(w0.x) + a1 * bfhi(w0.y) + a2 * bfhi(w0.z) + a3 * bfhi(w0.w)
            + a4 * bfhi(w1.x) + a5 * bfhi(w1.y) + a6 * bfhi(w1.z) + a7 * bfhi(w1.w);
    }
    #pragma unroll
    for (int m = 1; m < 64; m <<= 1) {
        z0 += __shfl_xor(z0, m);
        z1 += __shfl_xor(z1, m);
    }
    float si = s[row];
    float h = si * (z0 * W1[lane] + z1 * W1[64 + lane]) + b1[lane];
    h = fmaxf(h, 0.f);
    gT[(size_t)lane * N + row] = f2bf(si * h);
}

// Pass 4a: partial t = A @ g over a K-slab, LDS-staged GEMM.
// Grid (N/64, KSPLIT); block 256 = 4 waves; wave w owns rows w*16..w*16+15.
// LDS tiles [64][BK=64] bf16 (8 chunks/row), XOR swizzle ch^(row&7) applied
// on the inverse-swizzled global_load_lds source + swizzled ds_read (rule #21).
// Double-buffered: 32 KB LDS -> ~5 blocks/CU.
__global__ __launch_bounds__(256) void k_layer2a(const unsigned short* __restrict__ abf,
        const unsigned short* __restrict__ gT, float* __restrict__ tpart) {
    __shared__ unsigned short Al[2][64 * BK];   // 8 KB each
    __shared__ unsigned short Bl[2][64 * BK];
    int tid = threadIdx.x;
    int wave = tid >> 6, lane = tid & 63;
    int r0 = blockIdx.x * 64;
    int kbase0 = blockIdx.y * KPB;

    int r = lane & 15, q = lane >> 4;

    f32x4 acc0 = {0,0,0,0}, acc1 = {0,0,0,0}, acc2 = {0,0,0,0}, acc3 = {0,0,0,0};

    // 512 16B-chunks per operand per tile; 2 per thread. Lane-linear LDS dest,
    // inverse-swizzled global source (sch = ch ^ (srow&7)).
    #define STAGE(buf, kbase)                                                   \
        do {                                                                    \
            _Pragma("unroll")                                                   \
            for (int i = 0; i < 2; ++i) {                                       \
                int idx = i * 256 + tid;                                        \
                int srow = idx >> 3, sch = (idx & 7) ^ (srow & 7);              \
                glds16(abf + (size_t)(r0 + srow) * N + (kbase) + sch * 8,       \
                       &Al[buf][idx * 8]);                                      \
                glds16(gT + (size_t)srow * N + (kbase) + sch * 8,               \
                       &Bl[buf][idx * 8]);                                      \
            }                                                                   \
        } while (0)

    STAGE(0, kbase0);
    __syncthreads();

    for (int t = 0; t < TILES; ++t) {
        int cur = t & 1;
        if (t + 1 < TILES) STAGE(cur ^ 1, kbase0 + (t + 1) * BK);
        int arow = wave * 16 + r;
        #pragma unroll
        for (int ks = 0; ks < 2; ++ks) {            // K-steps of 32 within BK
            int cha = ((ks * 4 + q) ^ (arow & 7)) * 8;
            int chb = ((ks * 4 + q) ^ (r & 7)) * 8;
            sh8 a  = *(const sh8*)&Al[cur][arow * BK + cha];
            sh8 b0 = *(const sh8*)&Bl[cur][(r     ) * BK + chb];
            sh8 b1 = *(const sh8*)&Bl[cur][(r + 16) * BK + chb];
            sh8 b2 = *(const sh8*)&Bl[cur][(r + 32) * BK + chb];
            sh8 b3 = *(const sh8*)&Bl[cur][(r + 48) * BK + chb];
            acc0 = __builtin_amdgcn_mfma_f32_16x16x32_bf16(a, b0, acc0, 0, 0, 0);
            acc1 = __builtin_amdgcn_mfma_f32_16x16x32_bf16(a, b1, acc1, 0, 0, 0);
            acc2 = __builtin_amdgcn_mfma_f32_16x16x32_bf16(a, b2, acc2, 0, 0, 0);
            acc3 = __builtin_amdgcn_mfma_f32_16x16x32_bf16(a, b3, acc3, 0, 0, 0);
        }
        __syncthreads();   // drains vmcnt(0): next-tile stage has landed
    }
    #undef STAGE

    // C/D layout (m89-verified): col = lane&15, row = (lane>>4)*4 + reg
    float* tp = tpart + (size_t)blockIdx.y * N * 64;
    int growb = r0 + wave * 16 + q * 4;
    #pragma unroll
    for (int rr = 0; rr < 4; ++rr) {
        tp[(size_t)(growb + rr) * 64 + r     ] = acc0[rr];
        tp[(size_t)(growb + rr) * 64 + r + 16] = acc1[rr];
        tp[(size_t)(growb + rr) * 64 + r + 32] = acc2[rr];
        tp[(size_t)(growb + rr) * 64 + r + 48] = acc3[rr];
    }
}

// Pass 4b: t = sum of KSPLIT partials; out = s .* (t @ W2) + b2.
__global__ __launch_bounds__(256) void k_layer2b(const float* __restrict__ tpart,
        const float* __restrict__ s, const float* __restrict__ W2,
        const float* __restrict__ b2, float* __restrict__ out) {
    __shared__ float ts[4][64];
    int tid = threadIdx.x;
    int r0 = blockIdx.x * 4;
    int rg = tid >> 6, c = tid & 63;
    float v = 0.f;
    #pragma unroll
    for (int kb = 0; kb < KSPLIT; ++kb)
        v += tpart[(size_t)kb * N * 64 + (size_t)(r0 + rg) * 64 + c];
    ts[rg][c] = v;
    __syncthreads();
    float acc = 0.f;
    #pragma unroll 8
    for (int cc = 0; cc < 64; ++cc)
        acc += ts[rg][cc] * W2[cc * 64 + c];
    int row = r0 + rg;
    out[(size_t)row * 64 + c] = s[row] * acc + b2[c];
}

extern "C" void kernel_launch(void* const* d_in, const int* in_sizes, int n_in,
                              void* d_out, int out_size, void* d_ws, size_t ws_size,
                              hipStream_t stream) {
    const float* adj = (const float*)d_in[0];
    const float* W1  = (const float*)d_in[1];
    const float* b1  = (const float*)d_in[2];
    const float* W2  = (const float*)d_in[3];
    const float* b2  = (const float*)d_in[4];
    float* out = (float*)d_out;

    char* ws = (char*)d_ws;
    unsigned short* abf = (unsigned short*)ws;                              // 128 MB
    unsigned short* gT  = (unsigned short*)(ws + (size_t)N * N * 2);        // 1 MB
    float* tpart = (float*)(ws + (size_t)N * N * 2 + (size_t)64 * N * 2);   // 16 MB
    float* deg = tpart + (size_t)KSPLIT * N * 64;
    float* s   = deg + N;
    unsigned* yb = (unsigned*)(s + N);
    hipLaunchKernelGGL(k_deg_conv, dim3(N),      dim3(256),  0, stream, adj, abf, deg);
    hipLaunchKernelGGL(k_scalars,  dim3(1),      dim3(1024), 0, stream, deg, s, yb);
    hipLaunchKernelGGL(k_layer1,   dim3(N / 4),  dim3(256),  0, stream, abf, yb, s, W1, b1, gT);
    hipLaunchKernelGGL(k_layer2a,  dim3(N / 64, KSPLIT), dim3(256), 0, stream, abf, gT, tpart);
    hipLaunchKernelGGL(k_layer2b,  dim3(N / 4),  dim3(256),  0, stream, tpart, s, W2, b2, out);
}

// Round 8
// 118.201 us; speedup vs baseline: 8.0806x; 1.2034x over previous
//
#include <hip/hip_runtime.h>
#include <stdint.h>

#define N 8192
#define KSPLIT 8               // K-slabs for k_layer2a
#define BK 64                  // K elems per LDS tile
#define KPB (N / KSPLIT)       // 1024 K per block
#define TILES (KPB / BK)       // 16 tiles per block

typedef __attribute__((ext_vector_type(8))) short sh8;
typedef __attribute__((ext_vector_type(4))) float f32x4;
typedef __attribute__((ext_vector_type(2))) float f32x2;

static __device__ __forceinline__ unsigned short f2bf(float f) {
    union { float f; unsigned u; } v; v.f = f;
    unsigned r = v.u + 0x7FFF + ((v.u >> 16) & 1);   // round-to-nearest-even
    return (unsigned short)(r >> 16);
}

static __device__ __forceinline__ float bflo(unsigned u) {
    union { unsigned u; float f; } v; v.u = u << 16;
    return v.f;
}

static __device__ __forceinline__ float bfhi(unsigned u) {
    union { unsigned u; float f; } v; v.u = u & 0xFFFF0000u;
    return v.f;
}

static __device__ __forceinline__ unsigned fbits(float f) {
    union { float f; unsigned u; } v; v.f = f;
    return v.u;
}

static __device__ __forceinline__ void glds16(const void* g, void* l) {
    __builtin_amdgcn_global_load_lds(
        (const __attribute__((address_space(1))) void*)g,
        (__attribute__((address_space(3))) void*)l, 16, 0, 0);
}

// Pass 1: deg[i] = row-sum of adj (exact f32); write fp8 e4m3 copy of (adj + I).
__global__ __launch_bounds__(256) void k_deg_conv(const float* __restrict__ adj,
        unsigned char* __restrict__ abf, float* __restrict__ deg) {
    int row = blockIdx.x;
    const float* arow = adj + (size_t)row * N;
    unsigned* brow = (unsigned*)(abf + (size_t)row * N);
    int t = threadIdx.x;
    float sum = 0.f;
    #pragma unroll
    for (int it = 0; it < N / 1024; ++it) {      // 8 iters of float4 per thread
        int j = (it * 256 + t) * 4;
        float4 v = *(const float4*)(arow + j);
        sum += v.x + v.y + v.z + v.w;
        int d = row - j;                          // diag lands here iff d in [0,4)
        float x0 = v.x + ((d == 0) ? 1.f : 0.f);
        float x1 = v.y + ((d == 1) ? 1.f : 0.f);
        float x2 = v.z + ((d == 2) ? 1.f : 0.f);
        float x3 = v.w + ((d == 3) ? 1.f : 0.f);
        unsigned p = __builtin_amdgcn_cvt_pk_fp8_f32(x0, x1, 0, false);
        p = __builtin_amdgcn_cvt_pk_fp8_f32(x2, x3, p, true);
        brow[it * 256 + t] = p;                   // 4 fp8 per u32, coalesced
    }
    __shared__ float red[256];
    red[t] = sum; __syncthreads();
    for (int sz = 128; sz > 0; sz >>= 1) {
        if (t < sz) red[t] += red[t + sz];
        __syncthreads();
    }
    if (t == 0) deg[row] = red[0];
}

// Pass 2 (single block): gmax; s (f32); yb[j] = pack(bf16(y1), bf16(y0)).
__global__ __launch_bounds__(1024) void k_scalars(const float* __restrict__ deg,
        float* __restrict__ s, unsigned* __restrict__ yb) {
    __shared__ float red[1024];
    int t = threadIdx.x;
    float m = 1.0f;
    for (int i = t; i < N; i += 1024) m = fmaxf(m, deg[i]);
    red[t] = m; __syncthreads();
    for (int sz = 512; sz > 0; sz >>= 1) {
        if (t < sz) red[t] = fmaxf(red[t], red[t + sz]);
        __syncthreads();
    }
    float gmax = red[0];
    for (int i = t; i < N; i += 1024) {
        float d = deg[i];
        float si = 1.0f / sqrtf(fmaxf(d + 1.0f, 1.0f));
        s[i] = si;
        unsigned lo = f2bf(si);
        unsigned hi = f2bf(si * (d / gmax));
        yb[i] = (hi << 16) | lo;
    }
}

// Pass 3: one wave per row. z = a_row . [y0, y1] (a fp8, y packed bf16x2);
// h1 = relu(s_i*z@W1 + b1); store gT[c][i] = bf16(s_i * h1[i][c]).
__global__ __launch_bounds__(256) void k_layer1(const unsigned char* __restrict__ abf,
        const unsigned* __restrict__ yb, const float* __restrict__ s,
        const float* __restrict__ W1, const float* __restrict__ b1,
        unsigned short* __restrict__ gT) {
    int wave = threadIdx.x >> 6;
    int lane = threadIdx.x & 63;
    int row = blockIdx.x * 4 + wave;
    const unsigned char* arow = abf + (size_t)row * N;
    float z0 = 0.f, z1 = 0.f;
    #pragma unroll 4
    for (int it = 0; it < N / 512; ++it) {   // 16 iters, 8 elems/lane/iter
        int j = it * 512 + lane * 8;
        uint2 a8 = *(const uint2*)(arow + j);
        uint4 w0 = *(const uint4*)(yb + j);
        uint4 w1 = *(const uint4*)(yb + j + 4);
        f32x2 c01 = __builtin_amdgcn_cvt_pk_f32_fp8((int)a8.x, false);
        f32x2 c23 = __builtin_amdgcn_cvt_pk_f32_fp8((int)a8.x, true);
        f32x2 c45 = __builtin_amdgcn_cvt_pk_f32_fp8((int)a8.y, false);
        f32x2 c67 = __builtin_amdgcn_cvt_pk_f32_fp8((int)a8.y, true);
        z0 += c01.x * bflo(w0.x) + c01.y * bflo(w0.y)
            + c23.x * bflo(w0.z) + c23.y * bflo(w0.w)
            + c45.x * bflo(w1.x) + c45.y * bflo(w1.y)
            + c67.x * bflo(w1.z) + c67.y * bflo(w1.w);
        z1 += c01.x * bfhi(w0.x) + c01.y * bfhi(w0.y)
            + c23.x * bfhi(w0.z) + c23.y * bfhi(w0.w)
            + c45.x * bfhi(w1.x) + c45.y * bfhi(w1.y)
            + c67.x * bfhi(w1.z) + c67.y * bfhi(w1.w);
    }
    #pragma unroll
    for (int m = 1; m < 64; m <<= 1) {
        z0 += __shfl_xor(z0, m);
        z1 += __shfl_xor(z1, m);
    }
    float si = s[row];
    float h = si * (z0 * W1[lane] + z1 * W1[64 + lane]) + b1[lane];
    h = fmaxf(h, 0.f);
    gT[(size_t)lane * N + row] = f2bf(si * h);
}

// Pass 4a: partial t = A @ g over a K-slab. A fp8 in LDS (exact-converted to
// bf16 in regs), g bf16 in LDS; bf16 MFMA 16x16x32.
// Grid (N/64, KSPLIT); block 256 = 4 waves; wave w owns rows w*16..w*16+15.
// LDS: A [64][64B] (4 chunks/row, swz ch^(row&3)), B [64][128B] (8 chunks/row,
// swz ch^(row&7)); both inverse-swizzled at the global_load_lds source
// (rule #21). Double-buffered: 24 KB -> 6 blocks/CU LDS cap.
__global__ __launch_bounds__(256) void k_layer2a(const unsigned char* __restrict__ abf,
        const unsigned short* __restrict__ gT, float* __restrict__ tpart) {
    __shared__ unsigned char  Al[2][64 * 64];    // 4 KB each
    __shared__ unsigned short Bl[2][64 * 64];    // 8 KB each
    int tid = threadIdx.x;
    int wave = tid >> 6, lane = tid & 63;
    int r0 = blockIdx.x * 64;
    int kbase0 = blockIdx.y * KPB;

    int r = lane & 15, q = lane >> 4;

    f32x4 acc0 = {0,0,0,0}, acc1 = {0,0,0,0}, acc2 = {0,0,0,0}, acc3 = {0,0,0,0};

    // A: 256 16B-chunks/tile (1 per thread); B: 512 (2 per thread).
    #define STAGE(buf, kbase)                                                   \
        do {                                                                    \
            {                                                                   \
                int idx = tid;                                                  \
                int srow = idx >> 2, sch = (idx & 3) ^ (srow & 3);              \
                glds16(abf + (size_t)(r0 + srow) * N + (kbase) + sch * 16,      \
                       &Al[buf][idx * 16]);                                     \
            }                                                                   \
            _Pragma("unroll")                                                   \
            for (int i = 0; i < 2; ++i) {                                       \
                int idx = i * 256 + tid;                                        \
                int srow = idx >> 3, sch = (idx & 7) ^ (srow & 7);              \
                glds16(gT + (size_t)srow * N + (kbase) + sch * 8,               \
                       &Bl[buf][idx * 8]);                                      \
            }                                                                   \
        } while (0)

    STAGE(0, kbase0);
    __syncthreads();

    for (int t = 0; t < TILES; ++t) {
        int cur = t & 1;
        if (t + 1 < TILES) STAGE(cur ^ 1, kbase0 + (t + 1) * BK);
        int arow = wave * 16 + r;
        #pragma unroll
        for (int ks = 0; ks < 2; ++ks) {            // 2 K-steps of 32 per tile
            // A: k-octet ks*32+q*8 -> chunk (ks*2+(q>>1)) ^ (arow&3), half q&1
            int acho = (((ks * 2 + (q >> 1)) ^ (arow & 3)) * 16) + (q & 1) * 8;
            uint2 a8 = *(const uint2*)&Al[cur][arow * 64 + acho];
            f32x2 c01 = __builtin_amdgcn_cvt_pk_f32_fp8((int)a8.x, false);
            f32x2 c23 = __builtin_amdgcn_cvt_pk_f32_fp8((int)a8.x, true);
            f32x2 c45 = __builtin_amdgcn_cvt_pk_f32_fp8((int)a8.y, false);
            f32x2 c67 = __builtin_amdgcn_cvt_pk_f32_fp8((int)a8.y, true);
            // fp8 values are exactly representable in bf16: take high 16 bits.
            union { unsigned u[4]; sh8 v; } af;
            af.u[0] = (fbits(c01.y) & 0xFFFF0000u) | (fbits(c01.x) >> 16);
            af.u[1] = (fbits(c23.y) & 0xFFFF0000u) | (fbits(c23.x) >> 16);
            af.u[2] = (fbits(c45.y) & 0xFFFF0000u) | (fbits(c45.x) >> 16);
            af.u[3] = (fbits(c67.y) & 0xFFFF0000u) | (fbits(c67.x) >> 16);
            // B: k-octet -> chunk (ks*4+q) ^ (row&7); rows r+16k share r&7
            int chb = ((ks * 4 + q) ^ (r & 7)) * 8;
            sh8 b0 = *(const sh8*)&Bl[cur][(r     ) * 64 + chb];
            sh8 b1 = *(const sh8*)&Bl[cur][(r + 16) * 64 + chb];
            sh8 b2 = *(const sh8*)&Bl[cur][(r + 32) * 64 + chb];
            sh8 b3 = *(const sh8*)&Bl[cur][(r + 48) * 64 + chb];
            acc0 = __builtin_amdgcn_mfma_f32_16x16x32_bf16(af.v, b0, acc0, 0, 0, 0);
            acc1 = __builtin_amdgcn_mfma_f32_16x16x32_bf16(af.v, b1, acc1, 0, 0, 0);
            acc2 = __builtin_amdgcn_mfma_f32_16x16x32_bf16(af.v, b2, acc2, 0, 0, 0);
            acc3 = __builtin_amdgcn_mfma_f32_16x16x32_bf16(af.v, b3, acc3, 0, 0, 0);
        }
        __syncthreads();   // drains vmcnt(0): next-tile stage has landed
    }
    #undef STAGE

    // C/D layout (m89-verified): col = lane&15, row = (lane>>4)*4 + reg
    float* tp = tpart + (size_t)blockIdx.y * N * 64;
    int growb = r0 + wave * 16 + q * 4;
    #pragma unroll
    for (int rr = 0; rr < 4; ++rr) {
        tp[(size_t)(growb + rr) * 64 + r     ] = acc0[rr];
        tp[(size_t)(growb + rr) * 64 + r + 16] = acc1[rr];
        tp[(size_t)(growb + rr) * 64 + r + 32] = acc2[rr];
        tp[(size_t)(growb + rr) * 64 + r + 48] = acc3[rr];
    }
}

// Pass 4b: t = sum of KSPLIT partials; out = s .* (t @ W2) + b2.
__global__ __launch_bounds__(256) void k_layer2b(const float* __restrict__ tpart,
        const float* __restrict__ s, const float* __restrict__ W2,
        const float* __restrict__ b2, float* __restrict__ out) {
    __shared__ float ts[4][64];
    int tid = threadIdx.x;
    int r0 = blockIdx.x * 4;
    int rg = tid >> 6, c = tid & 63;
    float v = 0.f;
    #pragma unroll
    for (int kb = 0; kb < KSPLIT; ++kb)
        v += tpart[(size_t)kb * N * 64 + (size_t)(r0 + rg) * 64 + c];
    ts[rg][c] = v;
    __syncthreads();
    float acc = 0.f;
    #pragma unroll 8
    for (int cc = 0; cc < 64; ++cc)
        acc += ts[rg][cc] * W2[cc * 64 + c];
    int row = r0 + rg;
    out[(size_t)row * 64 + c] = s[row] * acc + b2[c];
}

extern "C" void kernel_launch(void* const* d_in, const int* in_sizes, int n_in,
                              void* d_out, int out_size, void* d_ws, size_t ws_size,
                              hipStream_t stream) {
    const float* adj = (const float*)d_in[0];
    const float* W1  = (const float*)d_in[1];
    const float* b1  = (const float*)d_in[2];
    const float* W2  = (const float*)d_in[3];
    const float* b2  = (const float*)d_in[4];
    float* out = (float*)d_out;

    char* ws = (char*)d_ws;
    unsigned char*  abf = (unsigned char*)ws;                               // 64 MB
    unsigned short* gT  = (unsigned short*)(ws + (size_t)N * N);            // 1 MB
    float* tpart = (float*)(ws + (size_t)N * N + (size_t)64 * N * 2);       // 16 MB
    float* deg = tpart + (size_t)KSPLIT * N * 64;
    float* s   = deg + N;
    unsigned* yb = (unsigned*)(s + N);

    hipLaunchKernelGGL(k_deg_conv, dim3(N),      dim3(256),  0, stream, adj, abf, deg);
    hipLaunchKernelGGL(k_scalars,  dim3(1),      dim3(1024), 0, stream, deg, s, yb);
    hipLaunchKernelGGL(k_layer1,   dim3(N / 4),  dim3(256),  0, stream, abf, yb, s, W1, b1, gT);
    hipLaunchKernelGGL(k_layer2a,  dim3(N / 64, KSPLIT), dim3(256), 0, stream, abf, gT, tpart);
    hipLaunchKernelGGL(k_layer2b,  dim3(N / 4),  dim3(256),  0, stream, tpart, s, W2, b2, out);
}